// Round 10
// baseline (295.408 us; speedup 1.0000x reference)
//
#include <hip/hip_runtime.h>

#define BSZ   16
#define LSEQ  4096
#define HCH   128
#define NST   64
#define NOUTD 128
#define TCH   64
#define NCHK  64

typedef unsigned long long u64;

// workspace float offsets
#define OFF_XT 0ull
#define OFF_U  8388608ull          // zT lives here (U no longer materialized)
#define OFF_S  16777216ull         // unused (kept for layout stability)
#define OFF_G  25165824ull
#define OFF_M  25690112ull
#define OFF_P  26214400ull
#define OFF_K  26738688ull
#define OFF_WT 26746880ull

// ---------------- K0: transpose x[b][l][h] -> xT[b][h][l] ----------------
__global__ __launch_bounds__(256) void k_tr_x(const float* __restrict__ x, float* __restrict__ xT){
  __shared__ float tile[64][65];
  int l0 = blockIdx.x*64, h0 = blockIdx.y*64, b = blockIdx.z;
  int tid = threadIdx.x;
  int tl = tid>>6, th = tid&63;
  #pragma unroll
  for (int k=0;k<16;k++){
    int l = tl + k*4;
    tile[l][th] = x[((u64)b*LSEQ + l0+l)*HCH + h0+th];
  }
  __syncthreads();
  #pragma unroll
  for (int k=0;k<16;k++){
    int hh = tl + k*4;
    xT[((u64)b*HCH + h0+hh)*LSEQ + l0+th] = tile[th][hh];
  }
}

// ---------------- K0b: transpose W[o][h] -> Wt[h][o] ----------------
__global__ __launch_bounds__(256) void k_tr_w(const float* __restrict__ W, float* __restrict__ Wt){
  int idx = blockIdx.x*256 + threadIdx.x;   // 0..16383
  int o = idx >> 7, h = idx & 127;
  Wt[h*NOUTD + o] = W[o*HCH + h];
}

// ---------------- K1: per-channel precompute (512 thr, Krylov doubling) ----------------
// Outputs: G[h][t][n] = (A_bar^{63-t} B_bar)[n]
//          Mx[h][t][n] = Wt[n][t]  (transposed store; k_ssm composes back)
//          P[h][i][j] = A_bar^64 ; ks[h][j] = C A_bar^j B_bar
__global__ __launch_bounds__(512) void k_pre(const float* __restrict__ A, const float* __restrict__ Bm,
                   const float* __restrict__ Cm, const float* __restrict__ log_dt,
                   float* __restrict__ G, float* __restrict__ Mx,
                   float* __restrict__ P, float* __restrict__ ks){
  __shared__ __align__(16) float Ls [64][68];   // lhs -> A_bar -> ping
  __shared__ __align__(16) float LsT[64][68];   // A_bar^T -> ping (transpose)
  __shared__ __align__(16) float Bb [64][68];   // pong
  __shared__ __align__(16) float BbT[64][68];   // pong (transpose)
  __shared__ __align__(16) float Vt [64][68];
  __shared__ __align__(16) float Wt [64][68];
  __shared__ float vbuf[64];
  __shared__ float cbuf[64];
  const int h = blockIdx.x, tid = threadIdx.x;
  const int lane = tid & 63, wid = tid >> 6;     // 8 waves
  const float dt = expf(log_dt[h]);

  // P0: lhs = I - 0.5*dt*A ; stage Bm, Cm
  for (int i = tid; i < 4096; i += 512){
    int r = i >> 6, c = i & 63;
    Ls[r][c] = ((r==c)?1.f:0.f) - 0.5f*dt*A[i];
  }
  if (tid < 64) vbuf[tid] = Bm[h*NST + tid];
  else if (tid < 128) cbuf[tid-64] = Cm[h*NST + (tid-64)];
  __syncthreads();

  // P1: forward substitution on wave 0 (col t of A_bar).
  float y[64];
  if (wid == 0){
    const int t = lane;
    #pragma unroll
    for (int j=0;j<64;j++) y[j] = 0.f;
    #pragma unroll
    for (int i=0;i<64;i++){
      float acc = ((i==t)?2.f:0.f) - Ls[i][t];
      #pragma unroll
      for (int j4=0;j4<(i+3)/4;j4++){
        float4 L4 = *(const float4*)&Ls[i][j4*4];
        acc -= L4.x*y[j4*4+0] + L4.y*y[j4*4+1] + L4.z*y[j4*4+2] + L4.w*y[j4*4+3];
      }
      y[i] = acc * (1.0f/Ls[i][i]);
    }
    #pragma unroll
    for (int i=0;i<64;i++){ Ls[i][t] = y[i]; LsT[t][i] = y[i]; }
  }
  __syncthreads();

  // P1b: seeds. wave0: Vt[0] = B_bar; wave1: Wt[0] = C*A_bar.
  if (wid == 0){
    const int t = lane;
    float a0=0.f,a1=0.f,a2=0.f,a3=0.f;
    #pragma unroll
    for (int m4=0;m4<16;m4++){
      float4 r4 = *(const float4*)&Ls[t][m4*4];
      a0 += r4.x*vbuf[m4*4+0]; a1 += r4.y*vbuf[m4*4+1];
      a2 += r4.z*vbuf[m4*4+2]; a3 += r4.w*vbuf[m4*4+3];
    }
    Vt[0][t] = 0.5f*dt*(((a0+a1)+(a2+a3)) + vbuf[t]);
  } else if (wid == 1){
    const int n = lane;
    float a0=0.f,a1=0.f,a2=0.f,a3=0.f;
    #pragma unroll
    for (int m4=0;m4<16;m4++){
      float4 c4 = *(const float4*)&LsT[n][m4*4];
      a0 += c4.x*cbuf[m4*4+0]; a1 += c4.y*cbuf[m4*4+1];
      a2 += c4.z*cbuf[m4*4+2]; a3 += c4.w*cbuf[m4*4+3];
    }
    Wt[0][n] = (a0+a1)+(a2+a3);
  }
  __syncthreads();

  // P2: 6 doubling steps.
  float (*cur)[68]  = Ls,  (*curT)[68] = LsT;
  float (*nxt)[68]  = Bb,  (*nxtT)[68] = BbT;
  for (int k=0;k<6;k++){
    const int nv = 1<<k;
    for (int j = tid; j < 32*nv; j += 512){
      const int isW = (j >= 16*nv);
      const int jj  = isW ? (j - 16*nv) : j;
      const int i   = jj >> 4;
      const int n0  = (jj & 15) << 2;
      float (*Xs)[68] = isW ? Wt  : Vt;
      float (*Ms)[68] = isW ? cur : curT;
      float o0=0.f,o1=0.f,o2=0.f,o3=0.f;
      #pragma unroll
      for (int m4=0;m4<16;m4++){
        const float4 xv = *(const float4*)&Xs[i][m4*4];
        const float4 c0 = *(const float4*)&Ms[m4*4+0][n0];
        const float4 c1 = *(const float4*)&Ms[m4*4+1][n0];
        const float4 c2 = *(const float4*)&Ms[m4*4+2][n0];
        const float4 c3 = *(const float4*)&Ms[m4*4+3][n0];
        o0 += xv.x*c0.x + xv.y*c1.x + xv.z*c2.x + xv.w*c3.x;
        o1 += xv.x*c0.y + xv.y*c1.y + xv.z*c2.y + xv.w*c3.y;
        o2 += xv.x*c0.z + xv.y*c1.z + xv.z*c2.z + xv.w*c3.z;
        o3 += xv.x*c0.w + xv.y*c1.w + xv.z*c2.w + xv.w*c3.w;
      }
      float* dst = isW ? &Wt[nv+i][n0] : &Vt[nv+i][n0];
      *(float4*)dst = make_float4(o0,o1,o2,o3);
    }
    {
      const int ti = (tid >> 4) << 1;
      const int tj = (tid & 15) << 2;
      float acc[2][4] = {};
      #pragma unroll
      for (int m4=0;m4<16;m4++){
        const float4 a0 = *(const float4*)&cur[ti+0][m4*4];
        const float4 a1 = *(const float4*)&cur[ti+1][m4*4];
        const float4 b0 = *(const float4*)&cur[m4*4+0][tj];
        const float4 b1 = *(const float4*)&cur[m4*4+1][tj];
        const float4 b2 = *(const float4*)&cur[m4*4+2][tj];
        const float4 b3 = *(const float4*)&cur[m4*4+3][tj];
        acc[0][0] += a0.x*b0.x + a0.y*b1.x + a0.z*b2.x + a0.w*b3.x;
        acc[0][1] += a0.x*b0.y + a0.y*b1.y + a0.z*b2.y + a0.w*b3.y;
        acc[0][2] += a0.x*b0.z + a0.y*b1.z + a0.z*b2.z + a0.w*b3.z;
        acc[0][3] += a0.x*b0.w + a0.y*b1.w + a0.z*b2.w + a0.w*b3.w;
        acc[1][0] += a1.x*b0.x + a1.y*b1.x + a1.z*b2.x + a1.w*b3.x;
        acc[1][1] += a1.x*b0.y + a1.y*b1.y + a1.z*b2.y + a1.w*b3.y;
        acc[1][2] += a1.x*b0.z + a1.y*b1.z + a1.z*b2.z + a1.w*b3.z;
        acc[1][3] += a1.x*b0.w + a1.y*b1.w + a1.z*b2.w + a1.w*b3.w;
      }
      *(float4*)&nxt[ti+0][tj] = make_float4(acc[0][0],acc[0][1],acc[0][2],acc[0][3]);
      *(float4*)&nxt[ti+1][tj] = make_float4(acc[1][0],acc[1][1],acc[1][2],acc[1][3]);
      #pragma unroll
      for (int e=0;e<4;e++){
        nxtT[tj+e][ti+0] = acc[0][e];
        nxtT[tj+e][ti+1] = acc[1][e];
      }
    }
    __syncthreads();
    { float (*t0)[68]=cur; cur=nxt;  nxt=t0; }
    { float (*t1)[68]=curT; curT=nxtT; nxtT=t1; }
  }

  // P3: outputs
  if (wid == 0){
    const int j = lane;
    float a0=0.f,a1=0.f,a2=0.f,a3=0.f;
    #pragma unroll
    for (int n4=0;n4<16;n4++){
      float4 v4 = *(const float4*)&Vt[j][n4*4];
      a0 += v4.x*cbuf[n4*4+0]; a1 += v4.y*cbuf[n4*4+1];
      a2 += v4.z*cbuf[n4*4+2]; a3 += v4.w*cbuf[n4*4+3];
    }
    ks[h*64 + j] = (a0+a1)+(a2+a3);
  }
  for (int idx = tid; idx < 4096; idx += 512){
    const int t = idx >> 6, n = idx & 63;
    G [(u64)h*4096 + idx] = Vt[63-t][n];
    Mx[(u64)h*4096 + idx] = Wt[n][t];   // transposed store
    P [(u64)h*4096 + idx] = cur[t][n];
  }
}

// ---------------- K2: fused proj + scan + zmix per (h,b) ----------------
// us: U[c][n] -> (in scan) S_before[c][n]. gs: G -> Toeplitz bb. ms[a][b]=M[b][a].
// z[c*64+t] = sum_j<=t k[t-j] x[c,j] + sum_n M[t][n] S[c][n] + D*x
__global__ __launch_bounds__(256) void k_ssm(const float* __restrict__ xT, const float* __restrict__ G,
                       const float* __restrict__ MxT, const float* __restrict__ P,
                       const float* __restrict__ ks, const float* __restrict__ D,
                       float* __restrict__ zT){
  __shared__ __align__(16) float xs[64][68];   // x[c][t]
  __shared__ __align__(16) float gs[64][68];   // G[t][n], later bb[j][t]
  __shared__ __align__(16) float ms[64][68];   // ms[n][t] = M[t][n]
  __shared__ __align__(16) float us[64][68];   // U[c][n] -> S[c][n]
  __shared__ float kv[64];
  const int h = blockIdx.x, b = blockIdx.y;
  const int tid = threadIdx.x, lane = tid & 63, wid = tid >> 6;

  const float* xb = xT + ((u64)b*HCH + h)*LSEQ;
  if (tid < 64) kv[tid] = ks[h*64 + tid];
  for (int i = tid; i < 4096; i += 256){
    xs[i>>6][i&63] = xb[i];
    gs[i>>6][i&63] = G  [(u64)h*4096 + i];
    ms[i>>6][i&63] = MxT[(u64)h*4096 + i];
  }
  __syncthreads();

  // ---- proj: U[c][n] = sum_t xs[c][t] * gs[t][n] ----
  const int tb = tid>>4, tn = tid&15;
  {
    float acc[4][4] = {};
    #pragma unroll 8
    for (int t=0;t<64;t++){
      float4 g4 = *(const float4*)&gs[t][tn*4];
      #pragma unroll
      for (int r=0;r<4;r++){
        float xv = xs[tb*4+r][t];
        acc[r][0] += xv*g4.x; acc[r][1] += xv*g4.y; acc[r][2] += xv*g4.z; acc[r][3] += xv*g4.w;
      }
    }
    #pragma unroll
    for (int r=0;r<4;r++)
      *(float4*)&us[tb*4+r][tn*4] = make_float4(acc[r][0],acc[r][1],acc[r][2],acc[r][3]);
  }
  __syncthreads();

  // ---- concurrent: waves 1-3 build Toeplitz bb into gs; wave 0 scans ----
  if (wid != 0){
    for (int i = tid-64; i < 4096; i += 192){
      int j = i>>6, t = i&63;
      gs[j][t] = (t>=j)? kv[t-j] : 0.f;
    }
  } else {
    // scan: s_c = P*s_{c-1} + u_c ; us[c] := s_{c-1}
    const float* Ph = P + (u64)h*4096;
    float prow[64];
    #pragma unroll
    for (int j4=0;j4<16;j4++){
      float4 p4 = *(const float4*)&Ph[lane*64 + j4*4];
      prow[j4*4+0]=p4.x; prow[j4*4+1]=p4.y; prow[j4*4+2]=p4.z; prow[j4*4+3]=p4.w;
    }
    float s = 0.f;
    for (int c=0;c<NCHK;c++){
      float u = us[c][lane];
      us[c][lane] = s;
      float a0=u, a1=0.f, a2=0.f, a3=0.f;
      #pragma unroll
      for (int j4=0;j4<16;j4++){
        float s0 = __uint_as_float(__builtin_amdgcn_readlane(__float_as_uint(s), j4*4+0));
        float s1 = __uint_as_float(__builtin_amdgcn_readlane(__float_as_uint(s), j4*4+1));
        float s2 = __uint_as_float(__builtin_amdgcn_readlane(__float_as_uint(s), j4*4+2));
        float s3 = __uint_as_float(__builtin_amdgcn_readlane(__float_as_uint(s), j4*4+3));
        a0 += s0*prow[j4*4+0]; a1 += s1*prow[j4*4+1];
        a2 += s2*prow[j4*4+2]; a3 += s3*prow[j4*4+3];
      }
      s = (a0+a1)+(a2+a3);
    }
  }
  __syncthreads();

  // ---- zmix: intra (bb in gs) + cross (ms, S in us) + D*x ----
  {
    float acc[4][4] = {};
    #pragma unroll 4
    for (int kk=0;kk<64;kk++){
      float4 b4 = *(const float4*)&gs[kk][tn*4];
      #pragma unroll
      for (int r=0;r<4;r++){
        float av = xs[tb*4+r][kk];
        acc[r][0]+=av*b4.x; acc[r][1]+=av*b4.y; acc[r][2]+=av*b4.z; acc[r][3]+=av*b4.w;
      }
    }
    #pragma unroll 4
    for (int kk=0;kk<64;kk++){
      float4 b4 = *(const float4*)&ms[kk][tn*4];
      #pragma unroll
      for (int r=0;r<4;r++){
        float sv = us[tb*4+r][kk];
        acc[r][0]+=sv*b4.x; acc[r][1]+=sv*b4.y; acc[r][2]+=sv*b4.z; acc[r][3]+=sv*b4.w;
      }
    }
    const float dv = D[h];
    float* zb = zT + ((u64)b*HCH + h)*LSEQ;
    #pragma unroll
    for (int r=0;r<4;r++){
      int c = tb*4+r;
      float4 o4;
      o4.x = acc[r][0] + dv*xs[c][tn*4+0];
      o4.y = acc[r][1] + dv*xs[c][tn*4+1];
      o4.z = acc[r][2] + dv*xs[c][tn*4+2];
      o4.w = acc[r][3] + dv*xs[c][tn*4+3];
      *(float4*)&zb[c*64 + tn*4] = o4;
    }
  }
}

// ---------------- K4b: out[b][l][o] = sum_h zT[b][h][l]*Wt[h][o] + bias[o] ----------------
__global__ __launch_bounds__(256) void k_out(const float* __restrict__ zT, const float* __restrict__ Wt,
                       const float* __restrict__ bias, float* __restrict__ out){
  int l0 = blockIdx.x*64, b = blockIdx.y;
  __shared__ __align__(16) float zl[128][64];
  int tid = threadIdx.x;
  for (int i=tid;i<8192;i+=256){
    int hh=i>>6, ll=i&63;
    zl[hh][ll] = zT[((u64)b*HCH + hh)*LSEQ + l0 + ll];
  }
  __syncthreads();
  int lane = tid&63, wid = tid>>6;
  int o = (wid&1)*64 + lane;
  int lq0 = (wid>>1)*32;
  float bo = bias[o];
  float acc[32];
  #pragma unroll
  for (int q=0;q<32;q++) acc[q] = bo;
  #pragma unroll 2
  for (int hh=0;hh<128;hh++){
    float wv = Wt[hh*NOUTD + o];
    #pragma unroll
    for (int q4=0;q4<8;q4++){
      float4 z4 = *(const float4*)&zl[hh][lq0 + q4*4];
      acc[q4*4+0] += wv*z4.x; acc[q4*4+1] += wv*z4.y; acc[q4*4+2] += wv*z4.z; acc[q4*4+3] += wv*z4.w;
    }
  }
  #pragma unroll
  for (int q=0;q<32;q++){
    out[((u64)b*LSEQ + l0 + lq0 + q)*NOUTD + o] = acc[q];
  }
}

extern "C" void kernel_launch(void* const* d_in, const int* in_sizes, int n_in,
                              void* d_out, int out_size, void* d_ws, size_t ws_size,
                              hipStream_t stream){
  const float* x      = (const float*)d_in[0];
  const float* A      = (const float*)d_in[1];
  const float* Bm     = (const float*)d_in[2];
  const float* Cm     = (const float*)d_in[3];
  const float* D      = (const float*)d_in[4];
  const float* log_dt = (const float*)d_in[5];
  const float* W      = (const float*)d_in[6];
  const float* bias   = (const float*)d_in[7];
  float* out = (float*)d_out;
  float* ws  = (float*)d_ws;

  float* xT  = ws + OFF_XT;
  float* zT  = ws + OFF_U;
  float* G   = ws + OFF_G;
  float* MxT = ws + OFF_M;
  float* P   = ws + OFF_P;
  float* ks  = ws + OFF_K;
  float* Wt  = ws + OFF_WT;

  hipLaunchKernelGGL(k_tr_x, dim3(64,2,16), dim3(256), 0, stream, x, xT);
  hipLaunchKernelGGL(k_tr_w, dim3(64),      dim3(256), 0, stream, W, Wt);
  hipLaunchKernelGGL(k_pre,  dim3(128),     dim3(512), 0, stream, A, Bm, Cm, log_dt, G, MxT, P, ks);
  hipLaunchKernelGGL(k_ssm,  dim3(128,16),  dim3(256), 0, stream, xT, G, MxT, P, ks, D, zT);
  hipLaunchKernelGGL(k_out,  dim3(64,16),   dim3(256), 0, stream, zT, Wt, bias, out);
}

// Round 11
// 277.553 us; speedup vs baseline: 1.0643x; 1.0643x over previous
//
#include <hip/hip_runtime.h>

#define BSZ   16
#define LSEQ  4096
#define HCH   128
#define NST   64
#define NOUTD 128
#define TCH   64
#define NCHK  64

typedef unsigned long long u64;

// workspace float offsets
#define OFF_XT 0ull
#define OFF_U  8388608ull          // zT lives here
#define OFF_S  16777216ull         // unused (layout stability)
#define OFF_G  25165824ull
#define OFF_M  25690112ull
#define OFF_P  26214400ull
#define OFF_K  26738688ull
#define OFF_WT 26746880ull

// ---------------- K0: transpose x[b][l][h] -> xT[b][h][l] ----------------
__global__ __launch_bounds__(256) void k_tr_x(const float* __restrict__ x, float* __restrict__ xT){
  __shared__ float tile[64][65];
  int l0 = blockIdx.x*64, h0 = blockIdx.y*64, b = blockIdx.z;
  int tid = threadIdx.x;
  int tl = tid>>6, th = tid&63;
  #pragma unroll
  for (int k=0;k<16;k++){
    int l = tl + k*4;
    tile[l][th] = x[((u64)b*LSEQ + l0+l)*HCH + h0+th];
  }
  __syncthreads();
  #pragma unroll
  for (int k=0;k<16;k++){
    int hh = tl + k*4;
    xT[((u64)b*HCH + h0+hh)*LSEQ + l0+th] = tile[th][hh];
  }
}

// ---------------- K0b: transpose W[o][h] -> Wt[h][o] ----------------
__global__ __launch_bounds__(256) void k_tr_w(const float* __restrict__ W, float* __restrict__ Wt){
  int idx = blockIdx.x*256 + threadIdx.x;   // 0..16383
  int o = idx >> 7, h = idx & 127;
  Wt[h*NOUTD + o] = W[o*HCH + h];
}

// ---------------- K1: per-channel precompute (512 thr, Krylov doubling) ----------------
// G[h][t][n] = (A_bar^{63-t} B_bar)[n] ; Mx[h][n][t] = (C A_bar^{t+1})[n] (transposed)
// P[h] = A_bar^64 ; ks[h][j] = C A_bar^j B_bar
__global__ __launch_bounds__(512) void k_pre(const float* __restrict__ A, const float* __restrict__ Bm,
                   const float* __restrict__ Cm, const float* __restrict__ log_dt,
                   float* __restrict__ G, float* __restrict__ Mx,
                   float* __restrict__ P, float* __restrict__ ks){
  __shared__ __align__(16) float Ls [64][68];
  __shared__ __align__(16) float LsT[64][68];
  __shared__ __align__(16) float Bb [64][68];
  __shared__ __align__(16) float BbT[64][68];
  __shared__ __align__(16) float Vt [64][68];
  __shared__ __align__(16) float Wt [64][68];
  __shared__ float vbuf[64];
  __shared__ float cbuf[64];
  const int h = blockIdx.x, tid = threadIdx.x;
  const int lane = tid & 63, wid = tid >> 6;
  const float dt = expf(log_dt[h]);

  for (int i = tid; i < 4096; i += 512){
    int r = i >> 6, c = i & 63;
    Ls[r][c] = ((r==c)?1.f:0.f) - 0.5f*dt*A[i];
  }
  if (tid < 64) vbuf[tid] = Bm[h*NST + tid];
  else if (tid < 128) cbuf[tid-64] = Cm[h*NST + (tid-64)];
  __syncthreads();

  float y[64];
  if (wid == 0){
    const int t = lane;
    #pragma unroll
    for (int j=0;j<64;j++) y[j] = 0.f;
    #pragma unroll
    for (int i=0;i<64;i++){
      float acc = ((i==t)?2.f:0.f) - Ls[i][t];
      #pragma unroll
      for (int j4=0;j4<(i+3)/4;j4++){
        float4 L4 = *(const float4*)&Ls[i][j4*4];
        acc -= L4.x*y[j4*4+0] + L4.y*y[j4*4+1] + L4.z*y[j4*4+2] + L4.w*y[j4*4+3];
      }
      y[i] = acc * (1.0f/Ls[i][i]);
    }
    #pragma unroll
    for (int i=0;i<64;i++){ Ls[i][t] = y[i]; LsT[t][i] = y[i]; }
  }
  __syncthreads();

  if (wid == 0){
    const int t = lane;
    float a0=0.f,a1=0.f,a2=0.f,a3=0.f;
    #pragma unroll
    for (int m4=0;m4<16;m4++){
      float4 r4 = *(const float4*)&Ls[t][m4*4];
      a0 += r4.x*vbuf[m4*4+0]; a1 += r4.y*vbuf[m4*4+1];
      a2 += r4.z*vbuf[m4*4+2]; a3 += r4.w*vbuf[m4*4+3];
    }
    Vt[0][t] = 0.5f*dt*(((a0+a1)+(a2+a3)) + vbuf[t]);
  } else if (wid == 1){
    const int n = lane;
    float a0=0.f,a1=0.f,a2=0.f,a3=0.f;
    #pragma unroll
    for (int m4=0;m4<16;m4++){
      float4 c4 = *(const float4*)&LsT[n][m4*4];
      a0 += c4.x*cbuf[m4*4+0]; a1 += c4.y*cbuf[m4*4+1];
      a2 += c4.z*cbuf[m4*4+2]; a3 += c4.w*cbuf[m4*4+3];
    }
    Wt[0][n] = (a0+a1)+(a2+a3);
  }
  __syncthreads();

  float (*cur)[68]  = Ls,  (*curT)[68] = LsT;
  float (*nxt)[68]  = Bb,  (*nxtT)[68] = BbT;
  for (int k=0;k<6;k++){
    const int nv = 1<<k;
    for (int j = tid; j < 32*nv; j += 512){
      const int isW = (j >= 16*nv);
      const int jj  = isW ? (j - 16*nv) : j;
      const int i   = jj >> 4;
      const int n0  = (jj & 15) << 2;
      float (*Xs)[68] = isW ? Wt  : Vt;
      float (*Ms)[68] = isW ? cur : curT;
      float o0=0.f,o1=0.f,o2=0.f,o3=0.f;
      #pragma unroll
      for (int m4=0;m4<16;m4++){
        const float4 xv = *(const float4*)&Xs[i][m4*4];
        const float4 c0 = *(const float4*)&Ms[m4*4+0][n0];
        const float4 c1 = *(const float4*)&Ms[m4*4+1][n0];
        const float4 c2 = *(const float4*)&Ms[m4*4+2][n0];
        const float4 c3 = *(const float4*)&Ms[m4*4+3][n0];
        o0 += xv.x*c0.x + xv.y*c1.x + xv.z*c2.x + xv.w*c3.x;
        o1 += xv.x*c0.y + xv.y*c1.y + xv.z*c2.y + xv.w*c3.y;
        o2 += xv.x*c0.z + xv.y*c1.z + xv.z*c2.z + xv.w*c3.z;
        o3 += xv.x*c0.w + xv.y*c1.w + xv.z*c2.w + xv.w*c3.w;
      }
      float* dst = isW ? &Wt[nv+i][n0] : &Vt[nv+i][n0];
      *(float4*)dst = make_float4(o0,o1,o2,o3);
    }
    {
      const int ti = (tid >> 4) << 1;
      const int tj = (tid & 15) << 2;
      float acc[2][4] = {};
      #pragma unroll
      for (int m4=0;m4<16;m4++){
        const float4 a0 = *(const float4*)&cur[ti+0][m4*4];
        const float4 a1 = *(const float4*)&cur[ti+1][m4*4];
        const float4 b0 = *(const float4*)&cur[m4*4+0][tj];
        const float4 b1 = *(const float4*)&cur[m4*4+1][tj];
        const float4 b2 = *(const float4*)&cur[m4*4+2][tj];
        const float4 b3 = *(const float4*)&cur[m4*4+3][tj];
        acc[0][0] += a0.x*b0.x + a0.y*b1.x + a0.z*b2.x + a0.w*b3.x;
        acc[0][1] += a0.x*b0.y + a0.y*b1.y + a0.z*b2.y + a0.w*b3.y;
        acc[0][2] += a0.x*b0.z + a0.y*b1.z + a0.z*b2.z + a0.w*b3.z;
        acc[0][3] += a0.x*b0.w + a0.y*b1.w + a0.z*b2.w + a0.w*b3.w;
        acc[1][0] += a1.x*b0.x + a1.y*b1.x + a1.z*b2.x + a1.w*b3.x;
        acc[1][1] += a1.x*b0.y + a1.y*b1.y + a1.z*b2.y + a1.w*b3.y;
        acc[1][2] += a1.x*b0.z + a1.y*b1.z + a1.z*b2.z + a1.w*b3.z;
        acc[1][3] += a1.x*b0.w + a1.y*b1.w + a1.z*b2.w + a1.w*b3.w;
      }
      *(float4*)&nxt[ti+0][tj] = make_float4(acc[0][0],acc[0][1],acc[0][2],acc[0][3]);
      *(float4*)&nxt[ti+1][tj] = make_float4(acc[1][0],acc[1][1],acc[1][2],acc[1][3]);
      #pragma unroll
      for (int e=0;e<4;e++){
        nxtT[tj+e][ti+0] = acc[0][e];
        nxtT[tj+e][ti+1] = acc[1][e];
      }
    }
    __syncthreads();
    { float (*t0)[68]=cur; cur=nxt;  nxt=t0; }
    { float (*t1)[68]=curT; curT=nxtT; nxtT=t1; }
  }

  if (wid == 0){
    const int j = lane;
    float a0=0.f,a1=0.f,a2=0.f,a3=0.f;
    #pragma unroll
    for (int n4=0;n4<16;n4++){
      float4 v4 = *(const float4*)&Vt[j][n4*4];
      a0 += v4.x*cbuf[n4*4+0]; a1 += v4.y*cbuf[n4*4+1];
      a2 += v4.z*cbuf[n4*4+2]; a3 += v4.w*cbuf[n4*4+3];
    }
    ks[h*64 + j] = (a0+a1)+(a2+a3);
  }
  for (int idx = tid; idx < 4096; idx += 512){
    const int t = idx >> 6, n = idx & 63;
    G [(u64)h*4096 + idx] = Vt[63-t][n];
    Mx[(u64)h*4096 + idx] = Wt[n][t];   // Mx[h][a][b] = M[b][a]
    P [(u64)h*4096 + idx] = cur[t][n];
  }
}

// ---------------- K2: fused proj + scan + zmix per (h,b), 512 thr, 3 blk/CU ----------------
// LDS: xs (x[c][t]), gs (G -> Toeplitz), us (U -> S_before). M read from GLOBAL MxT.
__global__ __launch_bounds__(512) void k_ssm(const float* __restrict__ xT, const float* __restrict__ G,
                       const float* __restrict__ MxT, const float* __restrict__ P,
                       const float* __restrict__ ks, const float* __restrict__ D,
                       float* __restrict__ zT){
  __shared__ __align__(16) float xs[64][68];
  __shared__ __align__(16) float gs[64][68];
  __shared__ __align__(16) float us[64][68];
  __shared__ float kv[64];
  const int h = blockIdx.x, b = blockIdx.y;
  const int tid = threadIdx.x, lane = tid & 63, wid = tid >> 6;   // 8 waves

  const float* xb = xT + ((u64)b*HCH + h)*LSEQ;
  const float* Mg = MxT + (u64)h*4096;
  if (tid < 64) kv[tid] = ks[h*64 + tid];
  for (int i = tid; i < 4096; i += 512){
    xs[i>>6][i&63] = xb[i];
    gs[i>>6][i&63] = G[(u64)h*4096 + i];
  }
  __syncthreads();

  // ---- proj: U[c][n] = sum_t xs[c][t] * gs[t][n] ; 2x4 tile / thread ----
  const int tb = tid>>4, tn = tid&15;     // tb 0..31, rows tb*2+r
  {
    float acc[2][4] = {};
    #pragma unroll 8
    for (int t=0;t<64;t++){
      float4 g4 = *(const float4*)&gs[t][tn*4];
      #pragma unroll
      for (int r=0;r<2;r++){
        float xv = xs[tb*2+r][t];
        acc[r][0] += xv*g4.x; acc[r][1] += xv*g4.y; acc[r][2] += xv*g4.z; acc[r][3] += xv*g4.w;
      }
    }
    #pragma unroll
    for (int r=0;r<2;r++)
      *(float4*)&us[tb*2+r][tn*4] = make_float4(acc[r][0],acc[r][1],acc[r][2],acc[r][3]);
  }
  __syncthreads();

  // ---- concurrent: wave 0 scans; waves 1-7 build Toeplitz into gs ----
  if (wid != 0){
    for (int i = tid-64; i < 4096; i += 448){
      int j = i>>6, t = i&63;
      gs[j][t] = (t>=j)? kv[t-j] : 0.f;
    }
  } else {
    const float* Ph = P + (u64)h*4096;
    float prow[64];
    #pragma unroll
    for (int j4=0;j4<16;j4++){
      float4 p4 = *(const float4*)&Ph[lane*64 + j4*4];
      prow[j4*4+0]=p4.x; prow[j4*4+1]=p4.y; prow[j4*4+2]=p4.z; prow[j4*4+3]=p4.w;
    }
    float s = 0.f;
    for (int c=0;c<NCHK;c++){
      float u = us[c][lane];
      us[c][lane] = s;
      float a0=u, a1=0.f, a2=0.f, a3=0.f;
      #pragma unroll
      for (int j4=0;j4<16;j4++){
        float s0 = __uint_as_float(__builtin_amdgcn_readlane(__float_as_uint(s), j4*4+0));
        float s1 = __uint_as_float(__builtin_amdgcn_readlane(__float_as_uint(s), j4*4+1));
        float s2 = __uint_as_float(__builtin_amdgcn_readlane(__float_as_uint(s), j4*4+2));
        float s3 = __uint_as_float(__builtin_amdgcn_readlane(__float_as_uint(s), j4*4+3));
        a0 += s0*prow[j4*4+0]; a1 += s1*prow[j4*4+1];
        a2 += s2*prow[j4*4+2]; a3 += s3*prow[j4*4+3];
      }
      s = (a0+a1)+(a2+a3);
    }
  }
  __syncthreads();

  // ---- zmix: intra (Toeplitz in gs) + cross (M from global, S in us) + D*x ----
  {
    float acc[2][4] = {};
    #pragma unroll 4
    for (int kk=0;kk<64;kk++){
      float4 b4 = *(const float4*)&gs[kk][tn*4];
      #pragma unroll
      for (int r=0;r<2;r++){
        float av = xs[tb*2+r][kk];
        acc[r][0]+=av*b4.x; acc[r][1]+=av*b4.y; acc[r][2]+=av*b4.z; acc[r][3]+=av*b4.w;
      }
    }
    #pragma unroll 4
    for (int kk=0;kk<64;kk++){
      float4 b4 = *(const float4*)&Mg[kk*64 + tn*4];   // M[t][kk] for t=tn*4..+3
      #pragma unroll
      for (int r=0;r<2;r++){
        float sv = us[tb*2+r][kk];
        acc[r][0]+=sv*b4.x; acc[r][1]+=sv*b4.y; acc[r][2]+=sv*b4.z; acc[r][3]+=sv*b4.w;
      }
    }
    const float dv = D[h];
    float* zb = zT + ((u64)b*HCH + h)*LSEQ;
    #pragma unroll
    for (int r=0;r<2;r++){
      int c = tb*2+r;
      float4 o4;
      o4.x = acc[r][0] + dv*xs[c][tn*4+0];
      o4.y = acc[r][1] + dv*xs[c][tn*4+1];
      o4.z = acc[r][2] + dv*xs[c][tn*4+2];
      o4.w = acc[r][3] + dv*xs[c][tn*4+3];
      *(float4*)&zb[c*64 + tn*4] = o4;
    }
  }
}

// ---------------- K4b: out[b][l][o] = sum_h zT[b][h][l]*Wt[h][o] + bias[o] ----------------
__global__ __launch_bounds__(256) void k_out(const float* __restrict__ zT, const float* __restrict__ Wt,
                       const float* __restrict__ bias, float* __restrict__ out){
  int l0 = blockIdx.x*64, b = blockIdx.y;
  __shared__ __align__(16) float zl[128][64];
  int tid = threadIdx.x;
  for (int i=tid;i<8192;i+=256){
    int hh=i>>6, ll=i&63;
    zl[hh][ll] = zT[((u64)b*HCH + hh)*LSEQ + l0 + ll];
  }
  __syncthreads();
  int lane = tid&63, wid = tid>>6;
  int o = (wid&1)*64 + lane;
  int lq0 = (wid>>1)*32;
  float bo = bias[o];
  float acc[32];
  #pragma unroll
  for (int q=0;q<32;q++) acc[q] = bo;
  #pragma unroll 2
  for (int hh=0;hh<128;hh++){
    float wv = Wt[hh*NOUTD + o];
    #pragma unroll
    for (int q4=0;q4<8;q4++){
      float4 z4 = *(const float4*)&zl[hh][lq0 + q4*4];
      acc[q4*4+0] += wv*z4.x; acc[q4*4+1] += wv*z4.y; acc[q4*4+2] += wv*z4.z; acc[q4*4+3] += wv*z4.w;
    }
  }
  #pragma unroll
  for (int q=0;q<32;q++){
    out[((u64)b*LSEQ + l0 + lq0 + q)*NOUTD + o] = acc[q];
  }
}

extern "C" void kernel_launch(void* const* d_in, const int* in_sizes, int n_in,
                              void* d_out, int out_size, void* d_ws, size_t ws_size,
                              hipStream_t stream){
  const float* x      = (const float*)d_in[0];
  const float* A      = (const float*)d_in[1];
  const float* Bm     = (const float*)d_in[2];
  const float* Cm     = (const float*)d_in[3];
  const float* D      = (const float*)d_in[4];
  const float* log_dt = (const float*)d_in[5];
  const float* W      = (const float*)d_in[6];
  const float* bias   = (const float*)d_in[7];
  float* out = (float*)d_out;
  float* ws  = (float*)d_ws;

  float* xT  = ws + OFF_XT;
  float* zT  = ws + OFF_U;
  float* G   = ws + OFF_G;
  float* MxT = ws + OFF_M;
  float* P   = ws + OFF_P;
  float* ks  = ws + OFF_K;
  float* Wt  = ws + OFF_WT;

  hipLaunchKernelGGL(k_tr_x, dim3(64,2,16), dim3(256), 0, stream, x, xT);
  hipLaunchKernelGGL(k_tr_w, dim3(64),      dim3(256), 0, stream, W, Wt);
  hipLaunchKernelGGL(k_pre,  dim3(128),     dim3(512), 0, stream, A, Bm, Cm, log_dt, G, MxT, P, ks);
  hipLaunchKernelGGL(k_ssm,  dim3(128,16),  dim3(512), 0, stream, xT, G, MxT, P, ks, D, zT);
  hipLaunchKernelGGL(k_out,  dim3(64,16),   dim3(256), 0, stream, zT, Wt, bias, out);
}